// Round 1
// baseline (336.157 us; speedup 1.0000x reference)
//
#include <hip/hip_runtime.h>
#include <math.h>

#define DIM 1024
#define NH 16
#define HD 64
#define SEQ 2048
#define CHUNK 128
#define NCHUNK (SEQ / CHUNK)   // 16
#define QKV_COLS (3 * DIM)     // 3072

// ---------------- GEMM: C[M][Nn] = A[M][K] @ W[Nn][K]^T (both row-major) ----
__global__ __launch_bounds__(256) void gemm_nt(const float* __restrict__ A,
                                               const float* __restrict__ W,
                                               float* __restrict__ C,
                                               int M, int Nn, int K) {
  __shared__ float As[16][64];
  __shared__ float Bs[16][64];
  const int tid = threadIdx.y * 16 + threadIdx.x;
  const int row0 = blockIdx.y * 64;
  const int col0 = blockIdx.x * 64;
  const int lr = tid >> 2;          // 0..63
  const int lk = (tid & 3) << 2;    // 0,4,8,12
  float acc[4][4] = {};
  for (int k0 = 0; k0 < K; k0 += 16) {
    float4 a4 = *reinterpret_cast<const float4*>(&A[(size_t)(row0 + lr) * K + k0 + lk]);
    float4 b4 = *reinterpret_cast<const float4*>(&W[(size_t)(col0 + lr) * K + k0 + lk]);
    __syncthreads();
    As[lk + 0][lr] = a4.x; As[lk + 1][lr] = a4.y;
    As[lk + 2][lr] = a4.z; As[lk + 3][lr] = a4.w;
    Bs[lk + 0][lr] = b4.x; Bs[lk + 1][lr] = b4.y;
    Bs[lk + 2][lr] = b4.z; Bs[lk + 3][lr] = b4.w;
    __syncthreads();
#pragma unroll
    for (int kk = 0; kk < 16; ++kk) {
      float a[4], b[4];
#pragma unroll
      for (int i = 0; i < 4; ++i) a[i] = As[kk][threadIdx.y * 4 + i];
#pragma unroll
      for (int j = 0; j < 4; ++j) b[j] = Bs[kk][threadIdx.x * 4 + j];
#pragma unroll
      for (int i = 0; i < 4; ++i)
#pragma unroll
        for (int j = 0; j < 4; ++j)
          acc[i][j] = fmaf(a[i], b[j], acc[i][j]);
    }
  }
#pragma unroll
  for (int i = 0; i < 4; ++i) {
    const int r = row0 + threadIdx.y * 4 + i;
#pragma unroll
    for (int j = 0; j < 4; ++j)
      C[(size_t)r * Nn + col0 + threadIdx.x * 4 + j] = acc[i][j];
  }
}

// -------- per-(head,chunk) KV outer-product sums: ckv[h][c][d][e] ----------
__global__ __launch_bounds__(256) void chunk_kv_kernel(const float* __restrict__ qkv,
                                                       float* __restrict__ ckv) {
  const int h = blockIdx.x / NCHUNK;
  const int c = blockIdx.x % NCHUNK;
  const int tid = threadIdx.x;
  __shared__ float pk[CHUNK][HD];
  __shared__ float vv[CHUNK][HD];
  for (int i = tid; i < CHUNK * HD / 4; i += 256) {
    const int r = i >> 4;
    const int d4 = (i & 15) << 2;
    const size_t base = (size_t)(c * CHUNK + r) * QKV_COLS + h * HD + d4;
    float4 k4 = *reinterpret_cast<const float4*>(&qkv[base + DIM]);
    float4 v4 = *reinterpret_cast<const float4*>(&qkv[base + 2 * DIM]);
    pk[r][d4 + 0] = fmaxf(k4.x, 0.f) + 1e-6f;
    pk[r][d4 + 1] = fmaxf(k4.y, 0.f) + 1e-6f;
    pk[r][d4 + 2] = fmaxf(k4.z, 0.f) + 1e-6f;
    pk[r][d4 + 3] = fmaxf(k4.w, 0.f) + 1e-6f;
    vv[r][d4 + 0] = v4.x; vv[r][d4 + 1] = v4.y;
    vv[r][d4 + 2] = v4.z; vv[r][d4 + 3] = v4.w;
  }
  __syncthreads();
  float acc[16];
#pragma unroll
  for (int p = 0; p < 16; ++p) acc[p] = 0.f;
  for (int r = 0; r < CHUNK; ++r) {
#pragma unroll
    for (int p = 0; p < 16; ++p) {
      const int lin = tid + p * 256;
      acc[p] = fmaf(pk[r][lin >> 6], vv[r][lin & 63], acc[p]);
    }
  }
  const size_t out_base = (size_t)(h * NCHUNK + c) * (HD * HD);
#pragma unroll
  for (int p = 0; p < 16; ++p) ckv[out_base + tid + p * 256] = acc[p];
}

// -------- in-place exclusive prefix over chunks (per head) -----------------
__global__ __launch_bounds__(256) void prefix_kernel(float* __restrict__ ckv) {
  const int h = blockIdx.x;
  const int tid = threadIdx.x;
#pragma unroll
  for (int p = 0; p < 16; ++p) {
    const int lin = tid + p * 256;
    float run = 0.f;
    for (int c = 0; c < NCHUNK; ++c) {
      const size_t idx = (size_t)(h * NCHUNK + c) * (HD * HD) + lin;
      const float t = ckv[idx];
      ckv[idx] = run;
      run += t;
    }
  }
}

// -------- per-(head,chunk) output: prefix-state part + intra-chunk causal --
__global__ __launch_bounds__(256) void attn_kernel(const float* __restrict__ qkv,
                                                   const float* __restrict__ ckv,
                                                   const float* __restrict__ alpha_log,
                                                   const float* __restrict__ beta_log,
                                                   float* __restrict__ attn_out) {
  const int h = blockIdx.x / NCHUNK;
  const int c = blockIdx.x % NCHUNK;
  const int tid = threadIdx.x;
  __shared__ float pq[CHUNK][HD];
  __shared__ float pk[CHUNK][HD];
  __shared__ float vv[CHUNK][HD];
  __shared__ float Sp[HD][HD];
  for (int i = tid; i < CHUNK * HD / 4; i += 256) {
    const int r = i >> 4;
    const int d4 = (i & 15) << 2;
    const size_t base = (size_t)(c * CHUNK + r) * QKV_COLS + h * HD + d4;
    float4 q4 = *reinterpret_cast<const float4*>(&qkv[base]);
    float4 k4 = *reinterpret_cast<const float4*>(&qkv[base + DIM]);
    float4 v4 = *reinterpret_cast<const float4*>(&qkv[base + 2 * DIM]);
    pq[r][d4 + 0] = fmaxf(q4.x, 0.f) + 1e-6f;
    pq[r][d4 + 1] = fmaxf(q4.y, 0.f) + 1e-6f;
    pq[r][d4 + 2] = fmaxf(q4.z, 0.f) + 1e-6f;
    pq[r][d4 + 3] = fmaxf(q4.w, 0.f) + 1e-6f;
    pk[r][d4 + 0] = fmaxf(k4.x, 0.f) + 1e-6f;
    pk[r][d4 + 1] = fmaxf(k4.y, 0.f) + 1e-6f;
    pk[r][d4 + 2] = fmaxf(k4.z, 0.f) + 1e-6f;
    pk[r][d4 + 3] = fmaxf(k4.w, 0.f) + 1e-6f;
    vv[r][d4 + 0] = v4.x; vv[r][d4 + 1] = v4.y;
    vv[r][d4 + 2] = v4.z; vv[r][d4 + 3] = v4.w;
  }
  {
    const size_t sbase = (size_t)(h * NCHUNK + c) * (HD * HD);
    float* sp = &Sp[0][0];
    for (int i = tid; i < HD * HD; i += 256) sp[i] = ckv[sbase + i];
  }
  __syncthreads();

  const int row = tid >> 1;           // 0..127
  const int e0 = (tid & 1) * 32;      // two threads split the 64 output dims
  float acc[32];
#pragma unroll
  for (int e = 0; e < 32; ++e) acc[e] = 0.f;

  // prefix-state contribution: acc[e] += phi_q[row][d] * Sp[d][e]
  for (int d = 0; d < HD; ++d) {
    const float qd = pq[row][d];
#pragma unroll
    for (int e = 0; e < 32; ++e) acc[e] = fmaf(qd, Sp[d][e0 + e], acc[e]);
  }
  // intra-chunk causal contribution
  for (int m = 0; m <= row; ++m) {
    float s = 0.f;
#pragma unroll
    for (int d = 0; d < HD; ++d) s = fmaf(pq[row][d], pk[m][d], s);
#pragma unroll
    for (int e = 0; e < 32; ++e) acc[e] = fmaf(s, vv[m][e0 + e], acc[e]);
  }

  // SteLLA normalization
  const float ap = log1pf(expf(alpha_log[h])) + 1e-6f;
  const float bp = log1pf(expf(beta_log[h])) + 1e-6f;
  const float scale = ap * bp * 8.0f;     // sqrt(HD)=8
  const int pos = c * CHUNK + row + 1;
  const float denom = fmaxf(scale * (float)pos, 1e-6f);
  const float inv = 1.0f / denom;

  const size_t obase = (size_t)(c * CHUNK + row) * DIM + h * HD + e0;
#pragma unroll
  for (int e = 0; e < 32; ++e) attn_out[obase + e] = acc[e] * inv;
}

extern "C" void kernel_launch(void* const* d_in, const int* in_sizes, int n_in,
                              void* d_out, int out_size, void* d_ws, size_t ws_size,
                              hipStream_t stream) {
  const float* x        = (const float*)d_in[0];
  const float* qkv_w    = (const float*)d_in[1];
  const float* proj_w   = (const float*)d_in[2];
  const float* alpha_lg = (const float*)d_in[3];
  const float* beta_lg  = (const float*)d_in[4];
  float* out = (float*)d_out;

  char* ws = (char*)d_ws;
  float* qkv  = (float*)ws;                                            // 2048*3072 f32 = 25.2 MB
  float* ckv  = (float*)(ws + (size_t)SEQ * QKV_COLS * 4);             // 16*16*64*64 f32 = 4.2 MB
  float* attn = (float*)(ws + (size_t)SEQ * QKV_COLS * 4
                            + (size_t)NH * NCHUNK * HD * HD * 4);      // 2048*1024 f32 = 8.4 MB

  dim3 blk(16, 16);
  // 1) qkv = x @ qkv_w^T
  gemm_nt<<<dim3(QKV_COLS / 64, SEQ / 64), blk, 0, stream>>>(x, qkv_w, qkv, SEQ, QKV_COLS, DIM);
  // 2) per-chunk KV sums
  chunk_kv_kernel<<<NH * NCHUNK, 256, 0, stream>>>(qkv, ckv);
  // 3) exclusive prefix over chunks
  prefix_kernel<<<NH, 256, 0, stream>>>(ckv);
  // 4) attention output + normalization
  attn_kernel<<<NH * NCHUNK, 256, 0, stream>>>(qkv, ckv, alpha_lg, beta_lg, attn);
  // 5) out = attn @ proj_w^T
  gemm_nt<<<dim3(DIM / 64, SEQ / 64), blk, 0, stream>>>(attn, proj_w, out, SEQ, DIM, DIM);
}

// Round 2
// 167.773 us; speedup vs baseline: 2.0036x; 2.0036x over previous
//
#include <hip/hip_runtime.h>
#include <math.h>

#define DIM 1024
#define NH 16
#define HD 64
#define SEQ 2048
#define CHUNK 128
#define NCHUNK (SEQ / CHUNK)   // 16
#define QKV_COLS (3 * DIM)     // 3072

typedef __attribute__((ext_vector_type(8))) short bf16x8;
typedef __attribute__((ext_vector_type(4))) float f32x4;

__device__ __forceinline__ unsigned short f2bf(float f) {
  unsigned int u = __float_as_uint(f);
  u += 0x7FFF + ((u >> 16) & 1);        // RNE
  return (unsigned short)(u >> 16);
}
__device__ __forceinline__ float bf2f(unsigned short s) {
  return __uint_as_float(((unsigned int)s) << 16);
}

// ---------------- f32 -> bf16 conversion (vectorized) ----------------------
__global__ __launch_bounds__(256) void convert_bf16(const float* __restrict__ in,
                                                    unsigned short* __restrict__ out,
                                                    int n4) {
  int i = blockIdx.x * 256 + threadIdx.x;
  if (i < n4) {
    float4 v = reinterpret_cast<const float4*>(in)[i];
    ushort4 o;
    o.x = f2bf(v.x); o.y = f2bf(v.y); o.z = f2bf(v.z); o.w = f2bf(v.w);
    reinterpret_cast<ushort4*>(out)[i] = o;
  }
}

// ---------------- bf16 MFMA GEMM (m97 structure): C = A @ W^T --------------
// A [M][K] bf16 row-major, W [Nn][K] bf16 row-major, C [M][Nn] (OutT)
template <typename OutT>
__global__ __launch_bounds__(256) void gemm_bt_bf16(const unsigned short* __restrict__ A,
                                                    const unsigned short* __restrict__ W,
                                                    OutT* __restrict__ C,
                                                    int M, int Nn, int K) {
  __shared__ unsigned short As[128 * 32];
  __shared__ unsigned short Bs[128 * 32];
  const int tid  = threadIdx.x;
  const int lane = tid & 63;
  const int wv   = tid >> 6;
  const int row0 = blockIdx.y * 128;
  const int col0 = blockIdx.x * 128;
  const int wr = (wv >> 1) * 64;
  const int wc = (wv & 1) * 64;

  f32x4 acc[4][4] = {};

  for (int k0 = 0; k0 < K; k0 += 32) {
#pragma unroll
    for (int t = 0; t < 2; ++t) {
      const int chunk = wv * 2 + t;          // 0..7, 1 KiB each
      const int lid = chunk * 64 + lane;     // 0..511
      const int r  = lid >> 2;               // 0..127
      const int ke = (lid & 3) << 3;         // 0,8,16,24
      __builtin_amdgcn_global_load_lds(
          (const __attribute__((address_space(1))) void*)&A[(size_t)(row0 + r) * K + k0 + ke],
          (__attribute__((address_space(3))) void*)&As[chunk * 512], 16, 0, 0);
      __builtin_amdgcn_global_load_lds(
          (const __attribute__((address_space(1))) void*)&W[(size_t)(col0 + r) * K + k0 + ke],
          (__attribute__((address_space(3))) void*)&Bs[chunk * 512], 16, 0, 0);
    }
    __syncthreads();   // drains vmcnt before reads

    bf16x8 a[4], b[4];
#pragma unroll
    for (int m = 0; m < 4; ++m)
      a[m] = *reinterpret_cast<const bf16x8*>(&As[(wr + m * 16 + (lane & 15)) * 32 + (lane >> 4) * 8]);
#pragma unroll
    for (int n = 0; n < 4; ++n)
      b[n] = *reinterpret_cast<const bf16x8*>(&Bs[(wc + n * 16 + (lane & 15)) * 32 + (lane >> 4) * 8]);
#pragma unroll
    for (int m = 0; m < 4; ++m)
#pragma unroll
      for (int n = 0; n < 4; ++n)
        acc[m][n] = __builtin_amdgcn_mfma_f32_16x16x32_bf16(a[m], b[n], acc[m][n], 0, 0, 0);
    __syncthreads();   // protect LDS before next stage
  }

  const int crow = (lane >> 4) * 4;   // m89-verified C/D layout
  const int ccol = lane & 15;
#pragma unroll
  for (int m = 0; m < 4; ++m)
#pragma unroll
    for (int n = 0; n < 4; ++n)
#pragma unroll
      for (int r = 0; r < 4; ++r) {
        const size_t idx = (size_t)(row0 + wr + m * 16 + crow + r) * Nn + col0 + wc + n * 16 + ccol;
        if constexpr (sizeof(OutT) == 2) C[idx] = (OutT)f2bf(acc[m][n][r]);
        else                             C[idx] = acc[m][n][r];
      }
}

// -------- per-(head,chunk) KV outer-product sums: ckv[h][c][d][e] ----------
__global__ __launch_bounds__(256) void chunk_kv_kernel(const unsigned short* __restrict__ qkv,
                                                       float* __restrict__ ckv) {
  const int h = blockIdx.x / NCHUNK;
  const int c = blockIdx.x % NCHUNK;
  const int tid = threadIdx.x;
  __shared__ float pk[CHUNK][HD];
  __shared__ float vv[CHUNK][HD];
  for (int i = tid; i < CHUNK * HD / 4; i += 256) {
    const int r = i >> 4;
    const int d4 = (i & 15) << 2;
    const size_t base = (size_t)(c * CHUNK + r) * QKV_COLS + h * HD + d4;
    ushort4 k4 = *reinterpret_cast<const ushort4*>(&qkv[base + DIM]);
    ushort4 v4 = *reinterpret_cast<const ushort4*>(&qkv[base + 2 * DIM]);
    pk[r][d4 + 0] = fmaxf(bf2f(k4.x), 0.f) + 1e-6f;
    pk[r][d4 + 1] = fmaxf(bf2f(k4.y), 0.f) + 1e-6f;
    pk[r][d4 + 2] = fmaxf(bf2f(k4.z), 0.f) + 1e-6f;
    pk[r][d4 + 3] = fmaxf(bf2f(k4.w), 0.f) + 1e-6f;
    vv[r][d4 + 0] = bf2f(v4.x); vv[r][d4 + 1] = bf2f(v4.y);
    vv[r][d4 + 2] = bf2f(v4.z); vv[r][d4 + 3] = bf2f(v4.w);
  }
  __syncthreads();
  float acc[16];
#pragma unroll
  for (int p = 0; p < 16; ++p) acc[p] = 0.f;
  for (int r = 0; r < CHUNK; ++r) {
#pragma unroll
    for (int p = 0; p < 16; ++p) {
      const int lin = tid + p * 256;
      acc[p] = fmaf(pk[r][lin >> 6], vv[r][lin & 63], acc[p]);
    }
  }
  const size_t out_base = (size_t)(h * NCHUNK + c) * (HD * HD);
#pragma unroll
  for (int p = 0; p < 16; ++p) ckv[out_base + tid + p * 256] = acc[p];
}

// -------- in-place exclusive prefix over chunks (per head) -----------------
__global__ __launch_bounds__(256) void prefix_kernel(float* __restrict__ ckv) {
  const int h = blockIdx.x;
  const int tid = threadIdx.x;
#pragma unroll
  for (int p = 0; p < 16; ++p) {
    const int lin = tid + p * 256;
    float run = 0.f;
    for (int c = 0; c < NCHUNK; ++c) {
      const size_t idx = (size_t)(h * NCHUNK + c) * (HD * HD) + lin;
      const float t = ckv[idx];
      ckv[idx] = run;
      run += t;
    }
  }
}

// -------- per-(head,chunk) output: prefix-state part + intra-chunk causal --
__global__ __launch_bounds__(256) void attn_kernel(const unsigned short* __restrict__ qkv,
                                                   const float* __restrict__ ckv,
                                                   const float* __restrict__ alpha_log,
                                                   const float* __restrict__ beta_log,
                                                   unsigned short* __restrict__ attn_out) {
  const int h = blockIdx.x / NCHUNK;
  const int c = blockIdx.x % NCHUNK;
  const int tid = threadIdx.x;
  // +1 pad: unpadded, pq[row][d] column reads put all 32 rows of a wave in
  // one bank (row stride = 256 B). Stride 65 floats spreads rows across banks.
  __shared__ float pq[CHUNK][HD + 1];
  __shared__ float pk[CHUNK][HD + 1];
  __shared__ float vv[CHUNK][HD + 1];
  __shared__ float Sp[HD][HD + 1];
  for (int i = tid; i < CHUNK * HD / 4; i += 256) {
    const int r = i >> 4;
    const int d4 = (i & 15) << 2;
    const size_t base = (size_t)(c * CHUNK + r) * QKV_COLS + h * HD + d4;
    ushort4 q4 = *reinterpret_cast<const ushort4*>(&qkv[base]);
    ushort4 k4 = *reinterpret_cast<const ushort4*>(&qkv[base + DIM]);
    ushort4 v4 = *reinterpret_cast<const ushort4*>(&qkv[base + 2 * DIM]);
    pq[r][d4 + 0] = fmaxf(bf2f(q4.x), 0.f) + 1e-6f;
    pq[r][d4 + 1] = fmaxf(bf2f(q4.y), 0.f) + 1e-6f;
    pq[r][d4 + 2] = fmaxf(bf2f(q4.z), 0.f) + 1e-6f;
    pq[r][d4 + 3] = fmaxf(bf2f(q4.w), 0.f) + 1e-6f;
    pk[r][d4 + 0] = fmaxf(bf2f(k4.x), 0.f) + 1e-6f;
    pk[r][d4 + 1] = fmaxf(bf2f(k4.y), 0.f) + 1e-6f;
    pk[r][d4 + 2] = fmaxf(bf2f(k4.z), 0.f) + 1e-6f;
    pk[r][d4 + 3] = fmaxf(bf2f(k4.w), 0.f) + 1e-6f;
    vv[r][d4 + 0] = bf2f(v4.x); vv[r][d4 + 1] = bf2f(v4.y);
    vv[r][d4 + 2] = bf2f(v4.z); vv[r][d4 + 3] = bf2f(v4.w);
  }
  {
    const size_t sbase = (size_t)(h * NCHUNK + c) * (HD * HD);
    for (int i = tid; i < HD * HD; i += 256) Sp[i >> 6][i & 63] = ckv[sbase + i];
  }
  __syncthreads();

  const int row = tid >> 1;           // 0..127
  const int e0 = (tid & 1) * 32;      // two threads split the 64 output dims
  float acc[32];
#pragma unroll
  for (int e = 0; e < 32; ++e) acc[e] = 0.f;

  // prefix-state contribution: acc[e] += phi_q[row][d] * Sp[d][e]
  for (int d = 0; d < HD; ++d) {
    const float qd = pq[row][d];
#pragma unroll
    for (int e = 0; e < 32; ++e) acc[e] = fmaf(qd, Sp[d][e0 + e], acc[e]);
  }
  // intra-chunk causal contribution
  for (int m = 0; m <= row; ++m) {
    float s = 0.f;
#pragma unroll
    for (int d = 0; d < HD; ++d) s = fmaf(pq[row][d], pk[m][d], s);
#pragma unroll
    for (int e = 0; e < 32; ++e) acc[e] = fmaf(s, vv[m][e0 + e], acc[e]);
  }

  // SteLLA normalization
  const float ap = log1pf(expf(alpha_log[h])) + 1e-6f;
  const float bp = log1pf(expf(beta_log[h])) + 1e-6f;
  const float scale = ap * bp * 8.0f;     // sqrt(HD)=8
  const int pos = c * CHUNK + row + 1;
  const float denom = fmaxf(scale * (float)pos, 1e-6f);
  const float inv = 1.0f / denom;

  const size_t obase = (size_t)(c * CHUNK + row) * DIM + h * HD + e0;
#pragma unroll
  for (int e = 0; e < 32; ++e) attn_out[obase + e] = f2bf(acc[e] * inv);
}

extern "C" void kernel_launch(void* const* d_in, const int* in_sizes, int n_in,
                              void* d_out, int out_size, void* d_ws, size_t ws_size,
                              hipStream_t stream) {
  const float* x        = (const float*)d_in[0];
  const float* qkv_w    = (const float*)d_in[1];
  const float* proj_w   = (const float*)d_in[2];
  const float* alpha_lg = (const float*)d_in[3];
  const float* beta_lg  = (const float*)d_in[4];
  float* out = (float*)d_out;

  char* ws = (char*)d_ws;
  size_t off = 0;
  unsigned short* qkvb = (unsigned short*)(ws + off); off += (size_t)SEQ * QKV_COLS * 2;   // 12.6 MB
  float*          ckv  = (float*)         (ws + off); off += (size_t)NH * NCHUNK * HD * HD * 4; // 4.2 MB
  unsigned short* attn = (unsigned short*)(ws + off); off += (size_t)SEQ * DIM * 2;        // 4.2 MB
  unsigned short* xb   = (unsigned short*)(ws + off); off += (size_t)SEQ * DIM * 2;        // 4.2 MB
  unsigned short* qwb  = (unsigned short*)(ws + off); off += (size_t)QKV_COLS * DIM * 2;   // 6.3 MB
  unsigned short* pwb  = (unsigned short*)(ws + off); off += (size_t)DIM * DIM * 2;        // 2.1 MB

  // 0) convert inputs to bf16
  convert_bf16<<<SEQ * DIM / 1024, 256, 0, stream>>>(x, xb, SEQ * DIM / 4);
  convert_bf16<<<QKV_COLS * DIM / 1024, 256, 0, stream>>>(qkv_w, qwb, QKV_COLS * DIM / 4);
  convert_bf16<<<DIM * DIM / 1024, 256, 0, stream>>>(proj_w, pwb, DIM * DIM / 4);
  // 1) qkv = x @ qkv_w^T (bf16 MFMA, bf16 out)
  gemm_bt_bf16<unsigned short><<<dim3(QKV_COLS / 128, SEQ / 128), 256, 0, stream>>>(
      xb, qwb, qkvb, SEQ, QKV_COLS, DIM);
  // 2) per-chunk KV sums
  chunk_kv_kernel<<<NH * NCHUNK, 256, 0, stream>>>(qkvb, ckv);
  // 3) exclusive prefix over chunks
  prefix_kernel<<<NH, 256, 0, stream>>>(ckv);
  // 4) attention output + normalization (bf16 out)
  attn_kernel<<<NH * NCHUNK, 256, 0, stream>>>(qkvb, ckv, alpha_lg, beta_lg, attn);
  // 5) out = attn @ proj_w^T (bf16 MFMA, f32 out)
  gemm_bt_bf16<float><<<dim3(DIM / 128, SEQ / 128), 256, 0, stream>>>(
      attn, pwb, out, SEQ, DIM, DIM);
}

// Round 3
// 100.256 us; speedup vs baseline: 3.3530x; 1.6734x over previous
//
#include <hip/hip_runtime.h>
#include <math.h>

#define DIM 1024
#define NH 16
#define HD 64
#define SEQ 2048
#define CHUNK 128
#define NCHUNK (SEQ / CHUNK)   // 16
#define QKV_COLS (3 * DIM)     // 3072

typedef __attribute__((ext_vector_type(8))) short bf16x8;
typedef __attribute__((ext_vector_type(4))) float f32x4;

__device__ __forceinline__ unsigned short f2bf(float f) {
  unsigned int u = __float_as_uint(f);
  u += 0x7FFF + ((u >> 16) & 1);        // RNE
  return (unsigned short)(u >> 16);
}
__device__ __forceinline__ float bf2f(unsigned short s) {
  return __uint_as_float(((unsigned int)s) << 16);
}
// XOR swizzle: spreads row-major tiles (row stride >=128B) across banks
__device__ __forceinline__ int swzb(int byte, int row) {
  return byte ^ ((row & 7) << 4);
}

// ---------------- f32 -> bf16 conversion (vectorized) ----------------------
__global__ __launch_bounds__(256) void convert_bf16(const float* __restrict__ in,
                                                    unsigned short* __restrict__ out,
                                                    int n4) {
  int i = blockIdx.x * 256 + threadIdx.x;
  if (i < n4) {
    float4 v = reinterpret_cast<const float4*>(in)[i];
    ushort4 o;
    o.x = f2bf(v.x); o.y = f2bf(v.y); o.z = f2bf(v.z); o.w = f2bf(v.w);
    reinterpret_cast<ushort4*>(out)[i] = o;
  }
}

// ---------------- bf16 MFMA GEMM (m97 structure): C = A @ W^T --------------
template <typename OutT>
__global__ __launch_bounds__(256) void gemm_bt_bf16(const unsigned short* __restrict__ A,
                                                    const unsigned short* __restrict__ W,
                                                    OutT* __restrict__ C,
                                                    int M, int Nn, int K) {
  __shared__ unsigned short As[128 * 32];
  __shared__ unsigned short Bs[128 * 32];
  const int tid  = threadIdx.x;
  const int lane = tid & 63;
  const int wv   = tid >> 6;
  const int row0 = blockIdx.y * 128;
  const int col0 = blockIdx.x * 128;
  const int wr = (wv >> 1) * 64;
  const int wc = (wv & 1) * 64;

  f32x4 acc[4][4] = {};

  for (int k0 = 0; k0 < K; k0 += 32) {
#pragma unroll
    for (int t = 0; t < 2; ++t) {
      const int chunk = wv * 2 + t;
      const int lid = chunk * 64 + lane;
      const int r  = lid >> 2;
      const int ke = (lid & 3) << 3;
      __builtin_amdgcn_global_load_lds(
          (const __attribute__((address_space(1))) void*)&A[(size_t)(row0 + r) * K + k0 + ke],
          (__attribute__((address_space(3))) void*)&As[chunk * 512], 16, 0, 0);
      __builtin_amdgcn_global_load_lds(
          (const __attribute__((address_space(1))) void*)&W[(size_t)(col0 + r) * K + k0 + ke],
          (__attribute__((address_space(3))) void*)&Bs[chunk * 512], 16, 0, 0);
    }
    __syncthreads();

    bf16x8 a[4], b[4];
#pragma unroll
    for (int m = 0; m < 4; ++m)
      a[m] = *reinterpret_cast<const bf16x8*>(&As[(wr + m * 16 + (lane & 15)) * 32 + (lane >> 4) * 8]);
#pragma unroll
    for (int n = 0; n < 4; ++n)
      b[n] = *reinterpret_cast<const bf16x8*>(&Bs[(wc + n * 16 + (lane & 15)) * 32 + (lane >> 4) * 8]);
#pragma unroll
    for (int m = 0; m < 4; ++m)
#pragma unroll
      for (int n = 0; n < 4; ++n)
        acc[m][n] = __builtin_amdgcn_mfma_f32_16x16x32_bf16(a[m], b[n], acc[m][n], 0, 0, 0);
    __syncthreads();
  }

  const int crow = (lane >> 4) * 4;
  const int ccol = lane & 15;
#pragma unroll
  for (int m = 0; m < 4; ++m)
#pragma unroll
    for (int n = 0; n < 4; ++n)
#pragma unroll
      for (int r = 0; r < 4; ++r) {
        const size_t idx = (size_t)(row0 + wr + m * 16 + crow + r) * Nn + col0 + wc + n * 16 + ccol;
        if constexpr (sizeof(OutT) == 2) C[idx] = (OutT)f2bf(acc[m][n][r]);
        else                             C[idx] = acc[m][n][r];
      }
}

// -------- per-(head,chunk) KV outer-product sums: ckv[h][c][d][e] ----------
__global__ __launch_bounds__(256) void chunk_kv_kernel(const unsigned short* __restrict__ qkv,
                                                       float* __restrict__ ckv) {
  const int h = blockIdx.x / NCHUNK;
  const int c = blockIdx.x % NCHUNK;
  const int tid = threadIdx.x;
  __shared__ float pk[CHUNK][HD];
  __shared__ float vv[CHUNK][HD];
  for (int i = tid; i < CHUNK * HD / 4; i += 256) {
    const int r = i >> 4;
    const int d4 = (i & 15) << 2;
    const size_t base = (size_t)(c * CHUNK + r) * QKV_COLS + h * HD + d4;
    ushort4 k4 = *reinterpret_cast<const ushort4*>(&qkv[base + DIM]);
    ushort4 v4 = *reinterpret_cast<const ushort4*>(&qkv[base + 2 * DIM]);
    pk[r][d4 + 0] = fmaxf(bf2f(k4.x), 0.f) + 1e-6f;
    pk[r][d4 + 1] = fmaxf(bf2f(k4.y), 0.f) + 1e-6f;
    pk[r][d4 + 2] = fmaxf(bf2f(k4.z), 0.f) + 1e-6f;
    pk[r][d4 + 3] = fmaxf(bf2f(k4.w), 0.f) + 1e-6f;
    vv[r][d4 + 0] = bf2f(v4.x); vv[r][d4 + 1] = bf2f(v4.y);
    vv[r][d4 + 2] = bf2f(v4.z); vv[r][d4 + 3] = bf2f(v4.w);
  }
  __syncthreads();
  float acc[16];
#pragma unroll
  for (int p = 0; p < 16; ++p) acc[p] = 0.f;
  for (int r = 0; r < CHUNK; ++r) {
#pragma unroll
    for (int p = 0; p < 16; ++p) {
      const int lin = tid + p * 256;
      acc[p] = fmaf(pk[r][lin >> 6], vv[r][lin & 63], acc[p]);
    }
  }
  const size_t out_base = (size_t)(h * NCHUNK + c) * (HD * HD);
#pragma unroll
  for (int p = 0; p < 16; ++p) ckv[out_base + tid + p * 256] = acc[p];
}

// -------- exclusive prefix over chunks (per head), 64-way parallel ---------
__global__ __launch_bounds__(256) void prefix_kernel(float* __restrict__ ckv) {
  const int h = blockIdx.x >> 2;
  const int lin = (blockIdx.x & 3) * 1024 + threadIdx.x * 4;
  float4 run = {0.f, 0.f, 0.f, 0.f};
  for (int cc = 0; cc < NCHUNK; ++cc) {
    float* p = &ckv[(size_t)(h * NCHUNK + cc) * (HD * HD) + lin];
    float4 t = *reinterpret_cast<float4*>(p);
    *reinterpret_cast<float4*>(p) = run;
    run.x += t.x; run.y += t.y; run.z += t.z; run.w += t.w;
  }
}

// -------- MFMA attention: S=phi_q@phi_k^T (masked) ; out = [phi_q,phi_q,P] @ [Sp_hi;Sp_lo;v]
__global__ __launch_bounds__(256) void attn_mfma_kernel(const unsigned short* __restrict__ qkv,
                                                        const float* __restrict__ ckv,
                                                        const float* __restrict__ alpha_log,
                                                        const float* __restrict__ beta_log,
                                                        unsigned short* __restrict__ attn_out) {
  const int h = blockIdx.x / NCHUNK;
  const int c = blockIdx.x % NCHUNK;
  const int tid  = threadIdx.x;
  const int lane = tid & 63;
  const int w    = tid >> 6;        // wave 0..3, owns rows w*32 .. w*32+31
  const int ln15 = lane & 15;
  const int lhi  = lane >> 4;       // 0..3

  __shared__ unsigned short ks[CHUNK * HD];      // phi_k [128][64] swizzled, 16 KB
  __shared__ unsigned short vst[HD * 256];       // V'^T  [e=64][k=256] swizzled, 32 KB
  __shared__ unsigned short ps[CHUNK * CHUNK];   // P     [128][128] swizzled, 32 KB

  // ---- stage 1: fill LDS + phi_q registers ----
  for (int i = tid; i < CHUNK * HD / 4; i += 256) {   // 8 iters
    const int r = i >> 4;
    const int d4 = (i & 15) << 2;
    const size_t base = (size_t)(c * CHUNK + r) * QKV_COLS + h * HD + d4;
    ushort4 k4 = *reinterpret_cast<const ushort4*>(&qkv[base + DIM]);
    ushort4 v4 = *reinterpret_cast<const ushort4*>(&qkv[base + 2 * DIM]);
    ushort4 pk4;
    pk4.x = f2bf(fmaxf(bf2f(k4.x), 0.f) + 1e-6f);
    pk4.y = f2bf(fmaxf(bf2f(k4.y), 0.f) + 1e-6f);
    pk4.z = f2bf(fmaxf(bf2f(k4.z), 0.f) + 1e-6f);
    pk4.w = f2bf(fmaxf(bf2f(k4.w), 0.f) + 1e-6f);
    *reinterpret_cast<ushort4*>((char*)ks + swzb(r * 128 + d4 * 2, r)) = pk4;  // swz flips bits 4-6, keeps 8B align
    // v transposed into vst[e][128+r]
#pragma unroll
    for (int j = 0; j < 4; ++j) {
      const int e = d4 + j;
      *reinterpret_cast<unsigned short*>((char*)vst + swzb(e * 512 + (128 + r) * 2, e)) = (&v4.x)[j];
    }
  }
  {
    const size_t sbase = (size_t)(h * NCHUNK + c) * (HD * HD);
    for (int i = tid; i < HD * HD / 4; i += 256) {    // 4 iters
      const int d = i >> 4;
      const int e4 = (i & 15) << 2;
      float4 s4 = *reinterpret_cast<const float4*>(&ckv[sbase + d * 64 + e4]);
#pragma unroll
      for (int j = 0; j < 4; ++j) {
        const float sv = (&s4.x)[j];
        const unsigned short hi = f2bf(sv);
        const unsigned short lo = f2bf(sv - bf2f(hi));
        const int e = e4 + j;
        *reinterpret_cast<unsigned short*>((char*)vst + swzb(e * 512 + d * 2, e)) = hi;
        *reinterpret_cast<unsigned short*>((char*)vst + swzb(e * 512 + (64 + d) * 2, e)) = lo;
      }
    }
  }
  // phi_q A-fragments in registers: rows w*32 + m*16 + ln15, k = kk*32 + lhi*8
  bf16x8 qf[2][2];
#pragma unroll
  for (int m = 0; m < 2; ++m)
#pragma unroll
    for (int kk = 0; kk < 2; ++kk) {
      const size_t gq = (size_t)(c * CHUNK + w * 32 + m * 16 + ln15) * QKV_COLS
                        + h * HD + kk * 32 + lhi * 8;
      bf16x8 raw = *reinterpret_cast<const bf16x8*>(&qkv[gq]);
#pragma unroll
      for (int j = 0; j < 8; ++j)
        raw[j] = (short)f2bf(fmaxf(bf2f((unsigned short)raw[j]), 0.f) + 1e-6f);
      qf[m][kk] = raw;
    }
  __syncthreads();

  // ---- stage 2: S = phi_q @ phi_k^T  (each wave: rows w*32..+31, all 8 col-tiles)
  f32x4 accs[2][8] = {};
#pragma unroll
  for (int j = 0; j < 8; ++j) {
    const int col = j * 16 + ln15;
    bf16x8 b0 = *reinterpret_cast<const bf16x8*>((char*)ks + swzb(col * 128 + lhi * 16, col));
    bf16x8 b1 = *reinterpret_cast<const bf16x8*>((char*)ks + swzb(col * 128 + 64 + lhi * 16, col));
#pragma unroll
    for (int m = 0; m < 2; ++m) {
      accs[m][j] = __builtin_amdgcn_mfma_f32_16x16x32_bf16(qf[m][0], b0, accs[m][j], 0, 0, 0);
      accs[m][j] = __builtin_amdgcn_mfma_f32_16x16x32_bf16(qf[m][1], b1, accs[m][j], 0, 0, 0);
    }
  }
  // mask (causal, diagonal inclusive) + convert + store P
#pragma unroll
  for (int m = 0; m < 2; ++m)
#pragma unroll
    for (int j = 0; j < 8; ++j)
#pragma unroll
      for (int r = 0; r < 4; ++r) {
        const int qrow = w * 32 + m * 16 + lhi * 4 + r;
        const int kcol = j * 16 + ln15;
        const float val = (qrow >= kcol) ? accs[m][j][r] : 0.f;
        *reinterpret_cast<unsigned short*>((char*)ps + swzb(qrow * 256 + kcol * 2, qrow)) = f2bf(val);
      }
  __syncthreads();

  // ---- stage 3: out = P' @ V'  (K = 256: [phi_q, phi_q, P] x [Sp_hi; Sp_lo; v])
  f32x4 acco[2][4] = {};
#pragma unroll
  for (int kk = 0; kk < 8; ++kk) {
    bf16x8 a[2];
    if (kk < 4) {
#pragma unroll
      for (int m = 0; m < 2; ++m) a[m] = qf[m][kk & 1];
    } else {
#pragma unroll
      for (int m = 0; m < 2; ++m) {
        const int row = w * 32 + m * 16 + ln15;
        a[m] = *reinterpret_cast<const bf16x8*>((char*)ps + swzb(row * 256 + (kk - 4) * 64 + lhi * 16, row));
      }
    }
#pragma unroll
    for (int ct = 0; ct < 4; ++ct) {
      const int e = ct * 16 + ln15;
      bf16x8 b = *reinterpret_cast<const bf16x8*>((char*)vst + swzb(e * 512 + kk * 64 + lhi * 16, e));
#pragma unroll
      for (int m = 0; m < 2; ++m)
        acco[m][ct] = __builtin_amdgcn_mfma_f32_16x16x32_bf16(a[m], b, acco[m][ct], 0, 0, 0);
    }
  }

  // ---- normalize + store ----
  const float ap = log1pf(expf(alpha_log[h])) + 1e-6f;
  const float bp = log1pf(expf(beta_log[h])) + 1e-6f;
  const float scale = ap * bp * 8.0f;     // sqrt(64)=8
#pragma unroll
  for (int m = 0; m < 2; ++m)
#pragma unroll
    for (int ct = 0; ct < 4; ++ct)
#pragma unroll
      for (int r = 0; r < 4; ++r) {
        const int n = c * CHUNK + w * 32 + m * 16 + lhi * 4 + r;
        const float inv = 1.0f / fmaxf(scale * (float)(n + 1), 1e-6f);
        attn_out[(size_t)n * DIM + h * HD + ct * 16 + ln15] = f2bf(acco[m][ct][r] * inv);
      }
}

extern "C" void kernel_launch(void* const* d_in, const int* in_sizes, int n_in,
                              void* d_out, int out_size, void* d_ws, size_t ws_size,
                              hipStream_t stream) {
  const float* x        = (const float*)d_in[0];
  const float* qkv_w    = (const float*)d_in[1];
  const float* proj_w   = (const float*)d_in[2];
  const float* alpha_lg = (const float*)d_in[3];
  const float* beta_lg  = (const float*)d_in[4];
  float* out = (float*)d_out;

  char* ws = (char*)d_ws;
  size_t off = 0;
  unsigned short* qkvb = (unsigned short*)(ws + off); off += (size_t)SEQ * QKV_COLS * 2;
  float*          ckv  = (float*)         (ws + off); off += (size_t)NH * NCHUNK * HD * HD * 4;
  unsigned short* attn = (unsigned short*)(ws + off); off += (size_t)SEQ * DIM * 2;
  unsigned short* xb   = (unsigned short*)(ws + off); off += (size_t)SEQ * DIM * 2;
  unsigned short* qwb  = (unsigned short*)(ws + off); off += (size_t)QKV_COLS * DIM * 2;
  unsigned short* pwb  = (unsigned short*)(ws + off); off += (size_t)DIM * DIM * 2;

  convert_bf16<<<SEQ * DIM / 1024, 256, 0, stream>>>(x, xb, SEQ * DIM / 4);
  convert_bf16<<<QKV_COLS * DIM / 1024, 256, 0, stream>>>(qkv_w, qwb, QKV_COLS * DIM / 4);
  convert_bf16<<<DIM * DIM / 1024, 256, 0, stream>>>(proj_w, pwb, DIM * DIM / 4);

  gemm_bt_bf16<unsigned short><<<dim3(QKV_COLS / 128, SEQ / 128), 256, 0, stream>>>(
      xb, qwb, qkvb, SEQ, QKV_COLS, DIM);

  chunk_kv_kernel<<<NH * NCHUNK, 256, 0, stream>>>(qkvb, ckv);
  prefix_kernel<<<NH * 4, 256, 0, stream>>>(ckv);
  attn_mfma_kernel<<<NH * NCHUNK, 256, 0, stream>>>(qkvb, ckv, alpha_lg, beta_lg, attn);

  gemm_bt_bf16<float><<<dim3(DIM / 128, SEQ / 128), 256, 0, stream>>>(
      attn, pwb, out, SEQ, DIM, DIM);
}

// Round 4
// 85.474 us; speedup vs baseline: 3.9328x; 1.1729x over previous
//
#include <hip/hip_runtime.h>
#include <math.h>

#define DIM 1024
#define NH 16
#define HD 64
#define SEQ 2048
#define CHUNK 128
#define NCHUNK (SEQ / CHUNK)   // 16
#define QKV_COLS (3 * DIM)     // 3072

typedef __attribute__((ext_vector_type(8))) short bf16x8;
typedef __attribute__((ext_vector_type(4))) float f32x4;

__device__ __forceinline__ unsigned short f2bf(float f) {
  unsigned int u = __float_as_uint(f);
  u += 0x7FFF + ((u >> 16) & 1);        // RNE
  return (unsigned short)(u >> 16);
}
__device__ __forceinline__ float bf2f(unsigned short s) {
  return __uint_as_float(((unsigned int)s) << 16);
}
// XOR swizzle: spreads row-major tiles (row stride >=128B) across banks
__device__ __forceinline__ int swzb(int byte, int row) {
  return byte ^ ((row & 7) << 4);
}

// ------------- fused f32 -> bf16 conversion for all three inputs -----------
__global__ __launch_bounds__(256) void convert_all(const float* __restrict__ x,
                                                   const float* __restrict__ qw,
                                                   const float* __restrict__ pw,
                                                   unsigned short* __restrict__ xb,
                                                   unsigned short* __restrict__ qwb,
                                                   unsigned short* __restrict__ pwb) {
  const int b = blockIdx.x;
  const float* in; unsigned short* out; int i;
  if (b < 2048)      { in = x;  out = xb;  i = b * 256 + threadIdx.x; }
  else if (b < 5120) { in = qw; out = qwb; i = (b - 2048) * 256 + threadIdx.x; }
  else               { in = pw; out = pwb; i = (b - 5120) * 256 + threadIdx.x; }
  float4 v = reinterpret_cast<const float4*>(in)[i];
  ushort4 o;
  o.x = f2bf(v.x); o.y = f2bf(v.y); o.z = f2bf(v.z); o.w = f2bf(v.w);
  reinterpret_cast<ushort4*>(out)[i] = o;
}

// ------- 2-phase double-buffered bf16 MFMA GEMM: C = A @ W^T ---------------
// BM=128 fixed; BN=128 (4 N-frags/wave) or BN=64 (2 N-frags/wave).
template <int BN, typename OutT>
__global__ __launch_bounds__(256) void gemm_bt_db(const unsigned short* __restrict__ A,
                                                  const unsigned short* __restrict__ W,
                                                  OutT* __restrict__ C,
                                                  int M, int Nn, int K) {
  constexpr int BM = 128;
  constexpr int BK = 32;
  constexpr int NFR = BN / 32;
  __shared__ unsigned short As[2][BM * BK];
  __shared__ unsigned short Bs[2][BN * BK];
  const int tid  = threadIdx.x;
  const int lane = tid & 63;
  const int wv   = tid >> 6;
  const int row0 = blockIdx.y * BM;
  const int col0 = blockIdx.x * BN;
  const int wr = (wv >> 1) * 64;
  const int wc = (wv & 1) * (BN / 2);

  f32x4 acc[4][NFR] = {};

  auto stage = [&](int buf, int t) {
    const int k0 = t * BK;
#pragma unroll
    for (int tt = 0; tt < 2; ++tt) {
      const int chunk = wv * 2 + tt;          // 0..7, 1 KiB each
      const int lid = chunk * 64 + lane;      // 0..511
      const int r  = lid >> 2;                // 0..127
      const int ke = (lid & 3) << 3;          // 0,8,16,24
      __builtin_amdgcn_global_load_lds(
          (const __attribute__((address_space(1))) void*)&A[(size_t)(row0 + r) * K + k0 + ke],
          (__attribute__((address_space(3))) void*)&As[buf][chunk * 512], 16, 0, 0);
    }
    if constexpr (BN == 128) {
#pragma unroll
      for (int tt = 0; tt < 2; ++tt) {
        const int chunk = wv * 2 + tt;
        const int lid = chunk * 64 + lane;
        const int r  = lid >> 2;
        const int ke = (lid & 3) << 3;
        __builtin_amdgcn_global_load_lds(
            (const __attribute__((address_space(1))) void*)&W[(size_t)(col0 + r) * K + k0 + ke],
            (__attribute__((address_space(3))) void*)&Bs[buf][chunk * 512], 16, 0, 0);
      }
    } else {
      const int lid = wv * 64 + lane;         // 0..255
      const int r  = lid >> 2;                // 0..63
      const int ke = (lid & 3) << 3;
      __builtin_amdgcn_global_load_lds(
          (const __attribute__((address_space(1))) void*)&W[(size_t)(col0 + r) * K + k0 + ke],
          (__attribute__((address_space(3))) void*)&Bs[buf][wv * 512], 16, 0, 0);
    }
  };

  const int nt = K / BK;
  stage(0, 0);
  __syncthreads();            // drains vmcnt(0): tile 0 landed
  int cur = 0;
  for (int t = 0; t < nt; ++t) {
    if (t + 1 < nt) stage(cur ^ 1, t + 1);   // issue next tile; drained at tail sync
    bf16x8 a[4], b[NFR];
#pragma unroll
    for (int m = 0; m < 4; ++m)
      a[m] = *reinterpret_cast<const bf16x8*>(&As[cur][(wr + m * 16 + (lane & 15)) * BK + (lane >> 4) * 8]);
#pragma unroll
    for (int n = 0; n < NFR; ++n)
      b[n] = *reinterpret_cast<const bf16x8*>(&Bs[cur][(wc + n * 16 + (lane & 15)) * BK + (lane >> 4) * 8]);
#pragma unroll
    for (int m = 0; m < 4; ++m)
#pragma unroll
      for (int n = 0; n < NFR; ++n)
        acc[m][n] = __builtin_amdgcn_mfma_f32_16x16x32_bf16(a[m], b[n], acc[m][n], 0, 0, 0);
    __syncthreads();          // drains this iter's stage loads + protects buffers
    cur ^= 1;
  }

  const int crow = (lane >> 4) * 4;   // m89-verified C/D layout
  const int ccol = lane & 15;
#pragma unroll
  for (int m = 0; m < 4; ++m)
#pragma unroll
    for (int n = 0; n < NFR; ++n)
#pragma unroll
      for (int r = 0; r < 4; ++r) {
        const size_t idx = (size_t)(row0 + wr + m * 16 + crow + r) * Nn + col0 + wc + n * 16 + ccol;
        if constexpr (sizeof(OutT) == 2) C[idx] = (OutT)f2bf(acc[m][n][r]);
        else                             C[idx] = acc[m][n][r];
      }
}

// -------- per-(head,chunk) KV outer-product sums: ckv[h][c][d][e] ----------
__global__ __launch_bounds__(256) void chunk_kv_kernel(const unsigned short* __restrict__ qkv,
                                                       float* __restrict__ ckv) {
  const int h = blockIdx.x / NCHUNK;
  const int c = blockIdx.x % NCHUNK;
  const int tid = threadIdx.x;
  __shared__ float pk[CHUNK][HD];
  __shared__ float vv[CHUNK][HD];
  for (int i = tid; i < CHUNK * HD / 4; i += 256) {
    const int r = i >> 4;
    const int d4 = (i & 15) << 2;
    const size_t base = (size_t)(c * CHUNK + r) * QKV_COLS + h * HD + d4;
    ushort4 k4 = *reinterpret_cast<const ushort4*>(&qkv[base + DIM]);
    ushort4 v4 = *reinterpret_cast<const ushort4*>(&qkv[base + 2 * DIM]);
    pk[r][d4 + 0] = fmaxf(bf2f(k4.x), 0.f) + 1e-6f;
    pk[r][d4 + 1] = fmaxf(bf2f(k4.y), 0.f) + 1e-6f;
    pk[r][d4 + 2] = fmaxf(bf2f(k4.z), 0.f) + 1e-6f;
    pk[r][d4 + 3] = fmaxf(bf2f(k4.w), 0.f) + 1e-6f;
    vv[r][d4 + 0] = bf2f(v4.x); vv[r][d4 + 1] = bf2f(v4.y);
    vv[r][d4 + 2] = bf2f(v4.z); vv[r][d4 + 3] = bf2f(v4.w);
  }
  __syncthreads();
  float acc[16];
#pragma unroll
  for (int p = 0; p < 16; ++p) acc[p] = 0.f;
  for (int r = 0; r < CHUNK; ++r) {
#pragma unroll
    for (int p = 0; p < 16; ++p) {
      const int lin = tid + p * 256;
      acc[p] = fmaf(pk[r][lin >> 6], vv[r][lin & 63], acc[p]);
    }
  }
  const size_t out_base = (size_t)(h * NCHUNK + c) * (HD * HD);
#pragma unroll
  for (int p = 0; p < 16; ++p) ckv[out_base + tid + p * 256] = acc[p];
}

// -------- exclusive prefix over chunks (per head), 64-way parallel ---------
__global__ __launch_bounds__(256) void prefix_kernel(float* __restrict__ ckv) {
  const int h = blockIdx.x >> 2;
  const int lin = (blockIdx.x & 3) * 1024 + threadIdx.x * 4;
  float4 run = {0.f, 0.f, 0.f, 0.f};
  for (int cc = 0; cc < NCHUNK; ++cc) {
    float* p = &ckv[(size_t)(h * NCHUNK + cc) * (HD * HD) + lin];
    float4 t = *reinterpret_cast<float4*>(p);
    *reinterpret_cast<float4*>(p) = run;
    run.x += t.x; run.y += t.y; run.z += t.z; run.w += t.w;
  }
}

// -------- MFMA attention: S=phi_q@phi_k^T (masked) ; out = [phi_q,phi_q,P] @ [Sp_hi;Sp_lo;v]
__global__ __launch_bounds__(256) void attn_mfma_kernel(const unsigned short* __restrict__ qkv,
                                                        const float* __restrict__ ckv,
                                                        const float* __restrict__ alpha_log,
                                                        const float* __restrict__ beta_log,
                                                        unsigned short* __restrict__ attn_out) {
  const int h = blockIdx.x / NCHUNK;
  const int c = blockIdx.x % NCHUNK;
  const int tid  = threadIdx.x;
  const int lane = tid & 63;
  const int w    = tid >> 6;        // wave 0..3, owns rows w*32 .. w*32+31
  const int ln15 = lane & 15;
  const int lhi  = lane >> 4;       // 0..3

  __shared__ unsigned short ks[CHUNK * HD];      // phi_k [128][64] swizzled, 16 KB
  __shared__ unsigned short vst[HD * 256];       // V'^T  [e=64][k=256] swizzled, 32 KB
  __shared__ unsigned short ps[CHUNK * CHUNK];   // P     [128][128] swizzled, 32 KB

  // ---- stage 1: fill LDS + phi_q registers ----
  for (int i = tid; i < CHUNK * HD / 4; i += 256) {   // 8 iters
    const int r = i >> 4;
    const int d4 = (i & 15) << 2;
    const size_t base = (size_t)(c * CHUNK + r) * QKV_COLS + h * HD + d4;
    ushort4 k4 = *reinterpret_cast<const ushort4*>(&qkv[base + DIM]);
    ushort4 v4 = *reinterpret_cast<const ushort4*>(&qkv[base + 2 * DIM]);
    ushort4 pk4;
    pk4.x = f2bf(fmaxf(bf2f(k4.x), 0.f) + 1e-6f);
    pk4.y = f2bf(fmaxf(bf2f(k4.y), 0.f) + 1e-6f);
    pk4.z = f2bf(fmaxf(bf2f(k4.z), 0.f) + 1e-6f);
    pk4.w = f2bf(fmaxf(bf2f(k4.w), 0.f) + 1e-6f);
    *reinterpret_cast<ushort4*>((char*)ks + swzb(r * 128 + d4 * 2, r)) = pk4;
#pragma unroll
    for (int j = 0; j < 4; ++j) {
      const int e = d4 + j;
      *reinterpret_cast<unsigned short*>((char*)vst + swzb(e * 512 + (128 + r) * 2, e)) = (&v4.x)[j];
    }
  }
  {
    const size_t sbase = (size_t)(h * NCHUNK + c) * (HD * HD);
    for (int i = tid; i < HD * HD / 4; i += 256) {    // 4 iters
      const int d = i >> 4;
      const int e4 = (i & 15) << 2;
      float4 s4 = *reinterpret_cast<const float4*>(&ckv[sbase + d * 64 + e4]);
#pragma unroll
      for (int j = 0; j < 4; ++j) {
        const float sv = (&s4.x)[j];
        const unsigned short hi = f2bf(sv);
        const unsigned short lo = f2bf(sv - bf2f(hi));
        const int e = e4 + j;
        *reinterpret_cast<unsigned short*>((char*)vst + swzb(e * 512 + d * 2, e)) = hi;
        *reinterpret_cast<unsigned short*>((char*)vst + swzb(e * 512 + (64 + d) * 2, e)) = lo;
      }
    }
  }
  bf16x8 qf[2][2];
#pragma unroll
  for (int m = 0; m < 2; ++m)
#pragma unroll
    for (int kk = 0; kk < 2; ++kk) {
      const size_t gq = (size_t)(c * CHUNK + w * 32 + m * 16 + ln15) * QKV_COLS
                        + h * HD + kk * 32 + lhi * 8;
      bf16x8 raw = *reinterpret_cast<const bf16x8*>(&qkv[gq]);
#pragma unroll
      for (int j = 0; j < 8; ++j)
        raw[j] = (short)f2bf(fmaxf(bf2f((unsigned short)raw[j]), 0.f) + 1e-6f);
      qf[m][kk] = raw;
    }
  __syncthreads();

  // ---- stage 2: S = phi_q @ phi_k^T ----
  f32x4 accs[2][8] = {};
#pragma unroll
  for (int j = 0; j < 8; ++j) {
    const int col = j * 16 + ln15;
    bf16x8 b0 = *reinterpret_cast<const bf16x8*>((char*)ks + swzb(col * 128 + lhi * 16, col));
    bf16x8 b1 = *reinterpret_cast<const bf16x8*>((char*)ks + swzb(col * 128 + 64 + lhi * 16, col));
#pragma unroll
    for (int m = 0; m < 2; ++m) {
      accs[m][j] = __builtin_amdgcn_mfma_f32_16x16x32_bf16(qf[m][0], b0, accs[m][j], 0, 0, 0);
      accs[m][j] = __builtin_amdgcn_mfma_f32_16x16x32_bf16(qf[m][1], b1, accs[m][j], 0, 0, 0);
    }
  }
#pragma unroll
  for (int m = 0; m < 2; ++m)
#pragma unroll
    for (int j = 0; j < 8; ++j)
#pragma unroll
      for (int r = 0; r < 4; ++r) {
        const int qrow = w * 32 + m * 16 + lhi * 4 + r;
        const int kcol = j * 16 + ln15;
        const float val = (qrow >= kcol) ? accs[m][j][r] : 0.f;
        *reinterpret_cast<unsigned short*>((char*)ps + swzb(qrow * 256 + kcol * 2, qrow)) = f2bf(val);
      }
  __syncthreads();

  // ---- stage 3: out = P' @ V'  (K = 256) ----
  f32x4 acco[2][4] = {};
#pragma unroll
  for (int kk = 0; kk < 8; ++kk) {
    bf16x8 a[2];
    if (kk < 4) {
#pragma unroll
      for (int m = 0; m < 2; ++m) a[m] = qf[m][kk & 1];
    } else {
#pragma unroll
      for (int m = 0; m < 2; ++m) {
        const int row = w * 32 + m * 16 + ln15;
        a[m] = *reinterpret_cast<const bf16x8*>((char*)ps + swzb(row * 256 + (kk - 4) * 64 + lhi * 16, row));
      }
    }
#pragma unroll
    for (int ct = 0; ct < 4; ++ct) {
      const int e = ct * 16 + ln15;
      bf16x8 b = *reinterpret_cast<const bf16x8*>((char*)vst + swzb(e * 512 + kk * 64 + lhi * 16, e));
#pragma unroll
      for (int m = 0; m < 2; ++m)
        acco[m][ct] = __builtin_amdgcn_mfma_f32_16x16x32_bf16(a[m], b, acco[m][ct], 0, 0, 0);
    }
  }

  // ---- normalize + store ----
  const float ap = log1pf(expf(alpha_log[h])) + 1e-6f;
  const float bp = log1pf(expf(beta_log[h])) + 1e-6f;
  const float scale = ap * bp * 8.0f;     // sqrt(64)=8
#pragma unroll
  for (int m = 0; m < 2; ++m)
#pragma unroll
    for (int ct = 0; ct < 4; ++ct)
#pragma unroll
      for (int r = 0; r < 4; ++r) {
        const int n = c * CHUNK + w * 32 + m * 16 + lhi * 4 + r;
        const float inv = 1.0f / fmaxf(scale * (float)(n + 1), 1e-6f);
        attn_out[(size_t)n * DIM + h * HD + ct * 16 + ln15] = f2bf(acco[m][ct][r] * inv);
      }
}

extern "C" void kernel_launch(void* const* d_in, const int* in_sizes, int n_in,
                              void* d_out, int out_size, void* d_ws, size_t ws_size,
                              hipStream_t stream) {
  const float* x        = (const float*)d_in[0];
  const float* qkv_w    = (const float*)d_in[1];
  const float* proj_w   = (const float*)d_in[2];
  const float* alpha_lg = (const float*)d_in[3];
  const float* beta_lg  = (const float*)d_in[4];
  float* out = (float*)d_out;

  char* ws = (char*)d_ws;
  size_t off = 0;
  unsigned short* qkvb = (unsigned short*)(ws + off); off += (size_t)SEQ * QKV_COLS * 2;
  float*          ckv  = (float*)         (ws + off); off += (size_t)NH * NCHUNK * HD * HD * 4;
  unsigned short* attn = (unsigned short*)(ws + off); off += (size_t)SEQ * DIM * 2;
  unsigned short* xb   = (unsigned short*)(ws + off); off += (size_t)SEQ * DIM * 2;
  unsigned short* qwb  = (unsigned short*)(ws + off); off += (size_t)QKV_COLS * DIM * 2;
  unsigned short* pwb  = (unsigned short*)(ws + off); off += (size_t)DIM * DIM * 2;

  // 0) fused bf16 conversion (x: 2048 blocks, qkv_w: 3072, proj_w: 1024)
  convert_all<<<6144, 256, 0, stream>>>(x, qkv_w, proj_w, xb, qwb, pwb);
  // 1) qkv = x @ qkv_w^T (double-buffered, 128x128 tile, 384 blocks)
  gemm_bt_db<128, unsigned short><<<dim3(QKV_COLS / 128, SEQ / 128), 256, 0, stream>>>(
      xb, qwb, qkvb, SEQ, QKV_COLS, DIM);
  // 2) per-chunk KV sums
  chunk_kv_kernel<<<NH * NCHUNK, 256, 0, stream>>>(qkvb, ckv);
  // 3) exclusive prefix over chunks
  prefix_kernel<<<NH * 4, 256, 0, stream>>>(ckv);
  // 4) attention output + normalization
  attn_mfma_kernel<<<NH * NCHUNK, 256, 0, stream>>>(qkvb, ckv, alpha_lg, beta_lg, attn);
  // 5) out = attn @ proj_w^T (double-buffered, 128x64 tile, 256 blocks = 1/CU)
  gemm_bt_db<64, float><<<dim3(DIM / 64, SEQ / 128), 256, 0, stream>>>(
      attn, pwb, out, SEQ, DIM, DIM);
}

// Round 5
// 77.842 us; speedup vs baseline: 4.3184x; 1.0980x over previous
//
#include <hip/hip_runtime.h>
#include <math.h>

#define DIM 1024
#define NH 16
#define HD 64
#define SEQ 2048
#define CHUNK 128
#define NCHUNK (SEQ / CHUNK)   // 16
#define QKV_COLS (3 * DIM)     // 3072

typedef __attribute__((ext_vector_type(8))) short bf16x8;
typedef __attribute__((ext_vector_type(4))) float f32x4;

__device__ __forceinline__ unsigned short f2bf(float f) {
  unsigned int u = __float_as_uint(f);
  u += 0x7FFF + ((u >> 16) & 1);        // RNE
  return (unsigned short)(u >> 16);
}
__device__ __forceinline__ float bf2f(unsigned short s) {
  return __uint_as_float(((unsigned int)s) << 16);
}
// XOR swizzle: spreads row-major tiles (row stride >=128B) across banks
__device__ __forceinline__ int swzb(int byte, int row) {
  return byte ^ ((row & 7) << 4);
}

// ------------- fused f32 -> bf16 conversion for all three inputs -----------
__global__ __launch_bounds__(256) void convert_all(const float* __restrict__ x,
                                                   const float* __restrict__ qw,
                                                   const float* __restrict__ pw,
                                                   unsigned short* __restrict__ xb,
                                                   unsigned short* __restrict__ qwb,
                                                   unsigned short* __restrict__ pwb) {
  const int b = blockIdx.x;
  const float* in; unsigned short* out; int i;
  if (b < 2048)      { in = x;  out = xb;  i = b * 256 + threadIdx.x; }
  else if (b < 5120) { in = qw; out = qwb; i = (b - 2048) * 256 + threadIdx.x; }
  else               { in = pw; out = pwb; i = (b - 5120) * 256 + threadIdx.x; }
  float4 v = reinterpret_cast<const float4*>(in)[i];
  ushort4 o;
  o.x = f2bf(v.x); o.y = f2bf(v.y); o.z = f2bf(v.z); o.w = f2bf(v.w);
  reinterpret_cast<ushort4*>(out)[i] = o;
}

// ------- triple-buffered counted-vmcnt bf16 MFMA GEMM: C = A @ W^T ---------
// BM=128 fixed; BN=128 (L=4 loads/wave/stage) or BN=64 (L=3).
template <int BN, typename OutT>
__global__ __launch_bounds__(256) void gemm3_bt(const unsigned short* __restrict__ A,
                                                const unsigned short* __restrict__ W,
                                                OutT* __restrict__ C,
                                                int M, int Nn, int K) {
  constexpr int BM = 128;
  constexpr int BK = 32;
  constexpr int NFR = BN / 32;
  __shared__ unsigned short As[3][BM * BK];   // 3 x 8 KB
  __shared__ unsigned short Bs[3][BN * BK];   // 3 x (8 or 4) KB
  const int tid  = threadIdx.x;
  const int lane = tid & 63;
  const int wv   = tid >> 6;
  const int row0 = blockIdx.y * BM;
  const int col0 = blockIdx.x * BN;
  const int wr = (wv >> 1) * 64;
  const int wc = (wv & 1) * (BN / 2);

  f32x4 acc[4][NFR] = {};

  auto stage = [&](int buf, int t) {
    const int k0 = t * BK;
#pragma unroll
    for (int tt = 0; tt < 2; ++tt) {
      const int chunk = wv * 2 + tt;          // 0..7, 1 KiB each
      const int lid = chunk * 64 + lane;      // 0..511
      const int r  = lid >> 2;                // 0..127
      const int ke = (lid & 3) << 3;          // 0,8,16,24
      __builtin_amdgcn_global_load_lds(
          (const __attribute__((address_space(1))) void*)&A[(size_t)(row0 + r) * K + k0 + ke],
          (__attribute__((address_space(3))) void*)&As[buf][chunk * 512], 16, 0, 0);
    }
    if constexpr (BN == 128) {
#pragma unroll
      for (int tt = 0; tt < 2; ++tt) {
        const int chunk = wv * 2 + tt;
        const int lid = chunk * 64 + lane;
        const int r  = lid >> 2;
        const int ke = (lid & 3) << 3;
        __builtin_amdgcn_global_load_lds(
            (const __attribute__((address_space(1))) void*)&W[(size_t)(col0 + r) * K + k0 + ke],
            (__attribute__((address_space(3))) void*)&Bs[buf][chunk * 512], 16, 0, 0);
      }
    } else {
      const int lid = wv * 64 + lane;         // 0..255
      const int r  = lid >> 2;                // 0..63
      const int ke = (lid & 3) << 3;
      __builtin_amdgcn_global_load_lds(
          (const __attribute__((address_space(1))) void*)&W[(size_t)(col0 + r) * K + k0 + ke],
          (__attribute__((address_space(3))) void*)&Bs[buf][wv * 512], 16, 0, 0);
    }
  };

  const int nt = K / BK;                       // 32
  stage(0, 0);
  stage(1, 1);
  // Ledger (per wave, L loads/stage): after prologue 2L outstanding.
  // iter t: vmcnt(L) => tile t landed (only newest stage may remain in
  // flight); barrier; stage(t+2) into buf (t+2)%3 (free: all waves passed
  // the barrier after reading it at iter t-1); compute tile t.
  for (int t = 0; t < nt; ++t) {
    if (t < nt - 1) {
      if constexpr (BN == 128) asm volatile("s_waitcnt vmcnt(4)" ::: "memory");
      else                     asm volatile("s_waitcnt vmcnt(3)" ::: "memory");
    } else {
      asm volatile("s_waitcnt vmcnt(0)" ::: "memory");
    }
    __builtin_amdgcn_s_barrier();
    if (t + 2 < nt) stage((t + 2) % 3, t + 2);
    const int cur = t % 3;
    bf16x8 a[4], b[NFR];
#pragma unroll
    for (int m = 0; m < 4; ++m)
      a[m] = *reinterpret_cast<const bf16x8*>(&As[cur][(wr + m * 16 + (lane & 15)) * BK + (lane >> 4) * 8]);
#pragma unroll
    for (int n = 0; n < NFR; ++n)
      b[n] = *reinterpret_cast<const bf16x8*>(&Bs[cur][(wc + n * 16 + (lane & 15)) * BK + (lane >> 4) * 8]);
#pragma unroll
    for (int m = 0; m < 4; ++m)
#pragma unroll
      for (int n = 0; n < NFR; ++n)
        acc[m][n] = __builtin_amdgcn_mfma_f32_16x16x32_bf16(a[m], b[n], acc[m][n], 0, 0, 0);
  }

  const int crow = (lane >> 4) * 4;   // m89-verified C/D layout
  const int ccol = lane & 15;
#pragma unroll
  for (int m = 0; m < 4; ++m)
#pragma unroll
    for (int n = 0; n < NFR; ++n)
#pragma unroll
      for (int r = 0; r < 4; ++r) {
        const size_t idx = (size_t)(row0 + wr + m * 16 + crow + r) * Nn + col0 + wc + n * 16 + ccol;
        if constexpr (sizeof(OutT) == 2) C[idx] = (OutT)f2bf(acc[m][n][r]);
        else                             C[idx] = acc[m][n][r];
      }
}

// -------- MFMA per-(head,chunk) KV sums: ckv[h][c][d][e] = sum_r phik[r][d] v[r][e]
__global__ __launch_bounds__(256) void ckv_mfma_kernel(const unsigned short* __restrict__ qkv,
                                                       float* __restrict__ ckv) {
  const int h = blockIdx.x / NCHUNK;
  const int c = blockIdx.x % NCHUNK;
  const int tid  = threadIdx.x;
  const int lane = tid & 63;
  const int w    = tid >> 6;        // wave = d-tile
  const int ln15 = lane & 15;
  const int lhi  = lane >> 4;

  __shared__ unsigned short kst[HD * CHUNK];   // phi_k^T [d][r] swizzled, 16 KB
  __shared__ unsigned short vt[HD * CHUNK];    // v^T     [e][r] swizzled, 16 KB

  for (int i = tid; i < CHUNK * HD / 4; i += 256) {   // 8 iters
    const int r = i >> 4;
    const int d4 = (i & 15) << 2;
    const size_t base = (size_t)(c * CHUNK + r) * QKV_COLS + h * HD + d4;
    ushort4 k4 = *reinterpret_cast<const ushort4*>(&qkv[base + DIM]);
    ushort4 v4 = *reinterpret_cast<const ushort4*>(&qkv[base + 2 * DIM]);
#pragma unroll
    for (int j = 0; j < 4; ++j) {
      const int d = d4 + j;
      *reinterpret_cast<unsigned short*>((char*)kst + swzb(d * 256 + r * 2, d)) =
          f2bf(fmaxf(bf2f((&k4.x)[j]), 0.f) + 1e-6f);
      *reinterpret_cast<unsigned short*>((char*)vt + swzb(d * 256 + r * 2, d)) = (&v4.x)[j];
    }
  }
  __syncthreads();

  f32x4 acc[4] = {};
#pragma unroll
  for (int ks = 0; ks < 4; ++ks) {
    const int dr = w * 16 + ln15;
    bf16x8 a = *reinterpret_cast<const bf16x8*>((char*)kst + swzb(dr * 256 + (ks * 32 + lhi * 8) * 2, dr));
#pragma unroll
    for (int et = 0; et < 4; ++et) {
      const int er = et * 16 + ln15;
      bf16x8 b = *reinterpret_cast<const bf16x8*>((char*)vt + swzb(er * 256 + (ks * 32 + lhi * 8) * 2, er));
      acc[et] = __builtin_amdgcn_mfma_f32_16x16x32_bf16(a, b, acc[et], 0, 0, 0);
    }
  }
  const size_t base = (size_t)(h * NCHUNK + c) * (HD * HD);
#pragma unroll
  for (int et = 0; et < 4; ++et)
#pragma unroll
    for (int r = 0; r < 4; ++r)
      ckv[base + (size_t)(w * 16 + lhi * 4 + r) * HD + et * 16 + ln15] = acc[et][r];
}

// -------- MFMA attention (with inline exclusive prefix over ckv chunks) ----
__global__ __launch_bounds__(256) void attn_mfma_kernel(const unsigned short* __restrict__ qkv,
                                                        const float* __restrict__ ckv,
                                                        const float* __restrict__ alpha_log,
                                                        const float* __restrict__ beta_log,
                                                        unsigned short* __restrict__ attn_out) {
  const int h = blockIdx.x / NCHUNK;
  const int c = blockIdx.x % NCHUNK;
  const int tid  = threadIdx.x;
  const int lane = tid & 63;
  const int w    = tid >> 6;        // wave 0..3, owns rows w*32 .. w*32+31
  const int ln15 = lane & 15;
  const int lhi  = lane >> 4;       // 0..3

  __shared__ unsigned short ks[CHUNK * HD];      // phi_k [128][64] swizzled, 16 KB
  __shared__ unsigned short vst[HD * 256];       // [e][k]: k=0..63 Sp_hi, 64..127 Sp_lo, 128..255 v^T; 32 KB
  __shared__ unsigned short ps[CHUNK * CHUNK];   // P     [128][128] swizzled, 32 KB

  // ---- stage 1a: inline exclusive prefix: Sp = sum_{cc<c} ckv[h][cc] ----
  float sp[16];
#pragma unroll
  for (int p = 0; p < 16; ++p) sp[p] = 0.f;
  {
    const float* cb = ckv + (size_t)h * NCHUNK * (HD * HD) + tid * 16;
    for (int cc = 0; cc < c; ++cc) {
      const float4* p4 = reinterpret_cast<const float4*>(cb + (size_t)cc * (HD * HD));
#pragma unroll
      for (int q = 0; q < 4; ++q) {
        float4 t = p4[q];
        sp[q * 4 + 0] += t.x; sp[q * 4 + 1] += t.y;
        sp[q * 4 + 2] += t.z; sp[q * 4 + 3] += t.w;
      }
    }
  }
  {
    // element idx = tid*16+j: d = idx>>6 (const per thread), e = idx&63
    const int d = tid >> 2;
#pragma unroll
    for (int j = 0; j < 16; ++j) {
      const int e = (tid & 3) * 16 + j;
      const float sv = sp[j];
      const unsigned short hi = f2bf(sv);
      const unsigned short lo = f2bf(sv - bf2f(hi));
      *reinterpret_cast<unsigned short*>((char*)vst + swzb(e * 512 + d * 2, e)) = hi;
      *reinterpret_cast<unsigned short*>((char*)vst + swzb(e * 512 + (64 + d) * 2, e)) = lo;
    }
  }

  // ---- stage 1b: K/V into LDS + phi_q registers ----
  for (int i = tid; i < CHUNK * HD / 4; i += 256) {   // 8 iters
    const int r = i >> 4;
    const int d4 = (i & 15) << 2;
    const size_t base = (size_t)(c * CHUNK + r) * QKV_COLS + h * HD + d4;
    ushort4 k4 = *reinterpret_cast<const ushort4*>(&qkv[base + DIM]);
    ushort4 v4 = *reinterpret_cast<const ushort4*>(&qkv[base + 2 * DIM]);
    ushort4 pk4;
    pk4.x = f2bf(fmaxf(bf2f(k4.x), 0.f) + 1e-6f);
    pk4.y = f2bf(fmaxf(bf2f(k4.y), 0.f) + 1e-6f);
    pk4.z = f2bf(fmaxf(bf2f(k4.z), 0.f) + 1e-6f);
    pk4.w = f2bf(fmaxf(bf2f(k4.w), 0.f) + 1e-6f);
    *reinterpret_cast<ushort4*>((char*)ks + swzb(r * 128 + d4 * 2, r)) = pk4;
#pragma unroll
    for (int j = 0; j < 4; ++j) {
      const int e = d4 + j;
      *reinterpret_cast<unsigned short*>((char*)vst + swzb(e * 512 + (128 + r) * 2, e)) = (&v4.x)[j];
    }
  }
  bf16x8 qf[2][2];
#pragma unroll
  for (int m = 0; m < 2; ++m)
#pragma unroll
    for (int kk = 0; kk < 2; ++kk) {
      const size_t gq = (size_t)(c * CHUNK + w * 32 + m * 16 + ln15) * QKV_COLS
                        + h * HD + kk * 32 + lhi * 8;
      bf16x8 raw = *reinterpret_cast<const bf16x8*>(&qkv[gq]);
#pragma unroll
      for (int j = 0; j < 8; ++j)
        raw[j] = (short)f2bf(fmaxf(bf2f((unsigned short)raw[j]), 0.f) + 1e-6f);
      qf[m][kk] = raw;
    }
  __syncthreads();

  // ---- stage 2: S = phi_q @ phi_k^T ----
  f32x4 accs[2][8] = {};
#pragma unroll
  for (int j = 0; j < 8; ++j) {
    const int col = j * 16 + ln15;
    bf16x8 b0 = *reinterpret_cast<const bf16x8*>((char*)ks + swzb(col * 128 + lhi * 16, col));
    bf16x8 b1 = *reinterpret_cast<const bf16x8*>((char*)ks + swzb(col * 128 + 64 + lhi * 16, col));
#pragma unroll
    for (int m = 0; m < 2; ++m) {
      accs[m][j] = __builtin_amdgcn_mfma_f32_16x16x32_bf16(qf[m][0], b0, accs[m][j], 0, 0, 0);
      accs[m][j] = __builtin_amdgcn_mfma_f32_16x16x32_bf16(qf[m][1], b1, accs[m][j], 0, 0, 0);
    }
  }
#pragma unroll
  for (int m = 0; m < 2; ++m)
#pragma unroll
    for (int j = 0; j < 8; ++j)
#pragma unroll
      for (int r = 0; r < 4; ++r) {
        const int qrow = w * 32 + m * 16 + lhi * 4 + r;
        const int kcol = j * 16 + ln15;
        const float val = (qrow >= kcol) ? accs[m][j][r] : 0.f;
        *reinterpret_cast<unsigned short*>((char*)ps + swzb(qrow * 256 + kcol * 2, qrow)) = f2bf(val);
      }
  __syncthreads();

  // ---- stage 3: out = [phi_q, phi_q, P] @ [Sp_hi; Sp_lo; v]  (K = 256) ----
  f32x4 acco[2][4] = {};
#pragma unroll
  for (int kk = 0; kk < 8; ++kk) {
    bf16x8 a[2];
    if (kk < 4) {
#pragma unroll
      for (int m = 0; m < 2; ++m) a[m] = qf[m][kk & 1];
    } else {
#pragma unroll
      for (int m = 0; m < 2; ++m) {
        const int row = w * 32 + m * 16 + ln15;
        a[m] = *reinterpret_cast<const bf16x8*>((char*)ps + swzb(row * 256 + (kk - 4) * 64 + lhi * 16, row));
      }
    }
#pragma unroll
    for (int ct = 0; ct < 4; ++ct) {
      const int e = ct * 16 + ln15;
      bf16x8 b = *reinterpret_cast<const bf16x8*>((char*)vst + swzb(e * 512 + kk * 64 + lhi * 16, e));
#pragma unroll
      for (int m = 0; m < 2; ++m)
        acco[m][ct] = __builtin_amdgcn_mfma_f32_16x16x32_bf16(a[m], b, acco[m][ct], 0, 0, 0);
    }
  }

  // ---- normalize + store ----
  const float ap = log1pf(expf(alpha_log[h])) + 1e-6f;
  const float bp = log1pf(expf(beta_log[h])) + 1e-6f;
  const float scale = ap * bp * 8.0f;     // sqrt(64)=8
#pragma unroll
  for (int m = 0; m < 2; ++m)
#pragma unroll
    for (int ct = 0; ct < 4; ++ct)
#pragma unroll
      for (int r = 0; r < 4; ++r) {
        const int n = c * CHUNK + w * 32 + m * 16 + lhi * 4 + r;
        const float inv = 1.0f / fmaxf(scale * (float)(n + 1), 1e-6f);
        attn_out[(size_t)n * DIM + h * HD + ct * 16 + ln15] = f2bf(acco[m][ct][r] * inv);
      }
}

extern "C" void kernel_launch(void* const* d_in, const int* in_sizes, int n_in,
                              void* d_out, int out_size, void* d_ws, size_t ws_size,
                              hipStream_t stream) {
  const float* x        = (const float*)d_in[0];
  const float* qkv_w    = (const float*)d_in[1];
  const float* proj_w   = (const float*)d_in[2];
  const float* alpha_lg = (const float*)d_in[3];
  const float* beta_lg  = (const float*)d_in[4];
  float* out = (float*)d_out;

  char* ws = (char*)d_ws;
  size_t off = 0;
  unsigned short* qkvb = (unsigned short*)(ws + off); off += (size_t)SEQ * QKV_COLS * 2;
  float*          ckv  = (float*)         (ws + off); off += (size_t)NH * NCHUNK * HD * HD * 4;
  unsigned short* attn = (unsigned short*)(ws + off); off += (size_t)SEQ * DIM * 2;
  unsigned short* xb   = (unsigned short*)(ws + off); off += (size_t)SEQ * DIM * 2;
  unsigned short* qwb  = (unsigned short*)(ws + off); off += (size_t)QKV_COLS * DIM * 2;
  unsigned short* pwb  = (unsigned short*)(ws + off); off += (size_t)DIM * DIM * 2;

  // 0) fused bf16 conversion
  convert_all<<<6144, 256, 0, stream>>>(x, qkv_w, proj_w, xb, qwb, pwb);
  // 1) qkv = x @ qkv_w^T (triple-buffered counted-vmcnt)
  gemm3_bt<128, unsigned short><<<dim3(QKV_COLS / 128, SEQ / 128), 256, 0, stream>>>(
      xb, qwb, qkvb, SEQ, QKV_COLS, DIM);
  // 2) per-chunk KV sums via MFMA
  ckv_mfma_kernel<<<NH * NCHUNK, 256, 0, stream>>>(qkvb, ckv);
  // 3) attention (inline prefix) + normalization
  attn_mfma_kernel<<<NH * NCHUNK, 256, 0, stream>>>(qkvb, ckv, alpha_lg, beta_lg, attn);
  // 4) out = attn @ proj_w^T (triple-buffered, 128x64 tile)
  gemm3_bt<64, float><<<dim3(DIM / 64, SEQ / 128), 256, 0, stream>>>(
      attn, pwb, out, SEQ, DIM, DIM);
}